// Round 1
// baseline (506.048 us; speedup 1.0000x reference)
//
#include <hip/hip_runtime.h>
#include <hip/hip_bf16.h>

// Performer-style linear attention: B=4, S=8192, H=768, NH=12, HD=64, M=64.
// Round 5: gemm_qkv / gemm_out rewritten as 256x256-tile BK=64 8-wave pipelined
// GEMMs (counted vmcnt(8) ledger, raw s_barrier, LDS XOR-swizzle chunk^=row&7
// applied via pre-swizzled global_load_lds source + swizzled ds_read, setprio
// around MFMA, bijective XCD swizzle). kv_accum grid 8->16 per bh.
// Pipeline:
//   K0 zero kvT[48][80][64]
//   K1 cvt hs -> bf16
//   K2 fold P into Wq/Wk (Wqp = Wq * blockdiag(P)) [fp32]
//   K3 build B^T concat weights [Wqp|Wkp|Wv] + WoT as bf16, bias
//   K4 bf16 GEMM QKV (256^2 pipelined) + fused maxexp epilogue -> qp row-major,
//      kpT [bh][m][n], vT [bh][d][n] transposed
//   K5 kv MFMA: kvT[bh][d][m] = sum_n vT[d][n] kpT[m][n]; row 64 = ksum
//   K6 ctx_gemm: acc = qp @ [kvT|ksum]^T, ctx = acc/(norm+eps) -> bf16
//   K7 bf16 GEMM (256^2 pipelined): out = ctx @ Wo + bo -> fp32

#define S_    8192
#define H_    768
#define NH_   12
#define EPS_  1e-6f

typedef unsigned short U16;
typedef short bf16x8 __attribute__((ext_vector_type(8)));
typedef float f32x4  __attribute__((ext_vector_type(4)));

__device__ __forceinline__ U16 f2b(float x) {            // fp32 -> bf16 RNE
  unsigned u = __float_as_uint(x);
  return (U16)((u + 0x7fffu + ((u >> 16) & 1u)) >> 16);
}
__device__ __forceinline__ float b2f(U16 h) {
  return __uint_as_float(((unsigned)h) << 16);
}
__device__ __forceinline__ void gl2lds16(const void* g, void* l) {
  __builtin_amdgcn_global_load_lds(
      (const __attribute__((address_space(1))) void*)g,
      (__attribute__((address_space(3))) void*)l, 16, 0, 0);
}

// ---------- K0: zero scratch ----------
__global__ void zero_f32(float* __restrict__ p, int n) {
  int i = blockIdx.x * 256 + threadIdx.x;
  if (i < n) p[i] = 0.f;
}

// ---------- K1: fp32 -> bf16 ----------
__global__ void cvt_f32_bf16(const float* __restrict__ src, U16* __restrict__ hi, int n4) {
  int i = blockIdx.x * 256 + threadIdx.x;
  if (i >= n4) return;
  float4 x = ((const float4*)src)[i];
  ushort4 h;
  h.x = f2b(x.x); h.y = f2b(x.y); h.z = f2b(x.z); h.w = f2b(x.w);
  ((ushort4*)hi)[i] = h;
}

// ---------- K2: fold P into Wq / Wk (and biases) ----------
__global__ void fold_proj(const float* __restrict__ Wq, const float* __restrict__ bq,
                          const float* __restrict__ Wk, const float* __restrict__ bk,
                          const float* __restrict__ P,
                          float* __restrict__ Wqp, float* __restrict__ bqp,
                          float* __restrict__ Wkp, float* __restrict__ bkp) {
  __shared__ float Pl[64 * 64];
  __shared__ float WL[4 * 64];
  int h = blockIdx.y, kc = blockIdx.x, tid = threadIdx.x;
  const float* W  = blockIdx.z ? Wk : Wq;
  const float* bb = blockIdx.z ? bk : bq;
  float* Wout = blockIdx.z ? Wkp : Wqp;
  float* bout = blockIdx.z ? bkp : bqp;
  const float4* P4 = (const float4*)(P + (size_t)h * 4096);
#pragma unroll
  for (int i = 0; i < 4; ++i) ((float4*)Pl)[tid + i * 256] = P4[tid + i * 256];
  WL[tid] = W[(size_t)(kc * 4 + (tid >> 6)) * H_ + h * 64 + (tid & 63)];
  __syncthreads();
  int kl = tid >> 6, m = tid & 63;
  float acc = 0.f;
#pragma unroll
  for (int d = 0; d < 64; ++d) acc += WL[kl * 64 + d] * Pl[d * 64 + m];
  Wout[(size_t)(kc * 4 + kl) * H_ + h * 64 + m] = acc;
  if (kc == 0 && tid < 64) {
    float a2 = 0.f;
    for (int d = 0; d < 64; ++d) a2 += bb[h * 64 + d] * Pl[d * 64 + tid];
    bout[h * 64 + tid] = a2;
  }
}

// ---------- K3: build B^T-layout weights as bf16 ----------
__global__ void build_cat(const float* __restrict__ Wqp, const float* __restrict__ Wkp,
                          const float* __restrict__ Wv,  const float* __restrict__ Wo,
                          U16* __restrict__ WcatH, U16* __restrict__ WoTH) {
  int k = blockIdx.x * 256 + threadIdx.x;
  int r = blockIdx.y;
  float v; U16* dh; size_t off;
  if (r < 768)       { v = Wqp[(size_t)k * H_ + r];          off = (size_t)r * H_ + k;          dh = WcatH; }
  else if (r < 1536) { v = Wkp[(size_t)k * H_ + (r - 768)];  off = (size_t)r * H_ + k;          dh = WcatH; }
  else if (r < 2304) { v = Wv [(size_t)k * H_ + (r - 1536)]; off = (size_t)r * H_ + k;          dh = WcatH; }
  else               { v = Wo [(size_t)k * H_ + (r - 2304)]; off = (size_t)(r - 2304) * H_ + k; dh = WoTH; }
  dh[off] = f2b(v);
}

__global__ void build_bias(const float* __restrict__ bqp, const float* __restrict__ bkp,
                           const float* __restrict__ bv, float* __restrict__ biasC) {
  int i = blockIdx.x * 256 + threadIdx.x;
  if (i >= 2304) return;
  biasC[i] = i < 768 ? bqp[i] : (i < 1536 ? bkp[i - 768] : bv[i - 1536]);
}

// ---------- K4: pipelined 256^2 bf16 GEMM + fused maxexp epilogue ----------
// C = A_bf16 @ B^T + bias. 256x256 tile, BK=64, 8 waves (2m x 4n), per-wave
// output 128x64 (exactly one head per wave). LDS 128 KB = 2 K-tile buffers.
// Ledger: stage tiles 0,1 (8 loads/wave each); per tile: vmcnt(8) [next tile's
// 8 loads stay in flight], s_barrier, 4 phases of {8 ds_read_b128, 16 MFMA},
// s_barrier, stage tile t+2 into freed buffer. XOR swizzle chunk^=(row&7) on
// both the global_load_lds source and the ds_read address.
__global__ __launch_bounds__(512, 2) void gemm_qkv(
    const U16* __restrict__ Ahi, const U16* __restrict__ Bhi,
    const float* __restrict__ bias,
    U16* __restrict__ qp, U16* __restrict__ kpT, U16* __restrict__ vT) {
  __shared__ __align__(16) U16 Us[65536];            // [buf][mat][256][64]
  const int tid = threadIdx.x, w = tid >> 6, lane = tid & 63;
  const int quad = lane >> 4, l16 = lane & 15;
  const int id = blockIdx.x;
  const int swz = (id & 7) * 144 + (id >> 3);        // 1152 = 8*144, bijective
  const int mt = swz & 127, nt = swz >> 7;
  const int rowA0 = mt * 256, colB0 = nt * 256;
  const int wm = w >> 2, wn = w & 3;
  const int srow = w * 8 + (lane >> 3);              // staging row in 64-group
  const int kch = ((lane & 7) ^ (lane >> 3)) * 8;    // pre-swizzled src chunk
  const U16* As = Ahi + (size_t)(rowA0 + srow) * H_ + kch;
  const U16* Bs = Bhi + (size_t)(colB0 + srow) * H_ + kch;
  const unsigned lb = (unsigned)(w * 8) * 64;

  f32x4 acc[8][4] = {};

  auto stage = [&](int kt, int bi) {
    const U16* ap = As + kt * 64;
    const U16* bp = Bs + kt * 64;
    unsigned ub = (unsigned)bi * 32768u + lb;
#pragma unroll
    for (int q = 0; q < 4; ++q) {
      gl2lds16(ap + (size_t)(q * 64) * H_, &Us[ub + q * 4096]);
      gl2lds16(bp + (size_t)(q * 64) * H_, &Us[ub + 16384u + q * 4096]);
    }
  };

  stage(0, 0);
  stage(1, 1);
  for (int t = 0; t < 12; ++t) {
    const unsigned ab = (unsigned)(t & 1) * 32768u;
    if (t < 11) asm volatile("s_waitcnt vmcnt(8)" ::: "memory");
    else        asm volatile("s_waitcnt vmcnt(0)" ::: "memory");
    __builtin_amdgcn_sched_barrier(0);
    __builtin_amdgcn_s_barrier();
    __builtin_amdgcn_sched_barrier(0);
#pragma unroll
    for (int ks = 0; ks < 2; ++ks) {
      const int xo = ks * 4 + quad;                  // global 16B-chunk index
#pragma unroll
      for (int mh = 0; mh < 2; ++mh) {
        bf16x8 ah[4], bh[4];
#pragma unroll
        for (int i = 0; i < 4; ++i) {
          int row = wm * 128 + mh * 64 + i * 16 + l16;
          ah[i] = *(const bf16x8*)&Us[ab + row * 64 + ((xo ^ (l16 & 7)) * 8)];
        }
#pragma unroll
        for (int j = 0; j < 4; ++j) {
          int row = wn * 64 + j * 16 + l16;
          bh[j] = *(const bf16x8*)&Us[ab + 16384u + row * 64 + ((xo ^ (l16 & 7)) * 8)];
        }
        __builtin_amdgcn_s_setprio(1);
#pragma unroll
        for (int j = 0; j < 4; ++j)
#pragma unroll
          for (int i = 0; i < 4; ++i)
            acc[mh * 4 + i][j] = __builtin_amdgcn_mfma_f32_16x16x32_bf16(
                ah[i], bh[j], acc[mh * 4 + i][j], 0, 0, 0);
        __builtin_amdgcn_s_setprio(0);
      }
    }
    __builtin_amdgcn_sched_barrier(0);
    __builtin_amdgcn_s_barrier();
    __builtin_amdgcn_sched_barrier(0);
    if (t + 2 < 12) stage(t + 2, t & 1);
  }

  // epilogue: each wave's 64-col range is exactly one head block
  const int col64 = colB0 + wn * 64;
  float bj[4];
#pragma unroll
  for (int j = 0; j < 4; ++j) bj[j] = bias[col64 + j * 16 + l16];
  if (col64 < 768) {                            // q logits -> row-major qp
    const int h = col64 >> 6;
#pragma unroll
    for (int f = 0; f < 8; ++f) {
#pragma unroll
      for (int r = 0; r < 4; ++r) {
        int row = rowA0 + wm * 128 + f * 16 + quad * 4 + r;
        float v0 = acc[f][0][r] + bj[0], v1 = acc[f][1][r] + bj[1];
        float v2 = acc[f][2][r] + bj[2], v3 = acc[f][3][r] + bj[3];
        float mx = fmaxf(fmaxf(v0, v1), fmaxf(v2, v3));
        mx = fmaxf(mx, __shfl_xor(mx, 1));
        mx = fmaxf(mx, __shfl_xor(mx, 2));
        mx = fmaxf(mx, __shfl_xor(mx, 4));
        mx = fmaxf(mx, __shfl_xor(mx, 8));
        int b = row >> 13, s = row & 8191;
        size_t base = ((size_t)(b * NH_ + h) * S_ + s) * 64 + l16;
        qp[base +  0] = f2b(__expf(v0 - mx));
        qp[base + 16] = f2b(__expf(v1 - mx));
        qp[base + 32] = f2b(__expf(v2 - mx));
        qp[base + 48] = f2b(__expf(v3 - mx));
      }
    }
  } else {                                      // k (exp) or v -> transposed
    const int isv = col64 >= 1536;
    const int h = (col64 - (isv ? 1536 : 768)) >> 6;
    U16* dstT = isv ? vT : kpT;
#pragma unroll
    for (int f = 0; f < 8; ++f) {
      float er[4][4];                           // [j][r]
#pragma unroll
      for (int r = 0; r < 4; ++r) {
        float v0 = acc[f][0][r] + bj[0], v1 = acc[f][1][r] + bj[1];
        float v2 = acc[f][2][r] + bj[2], v3 = acc[f][3][r] + bj[3];
        if (!isv) {
          float mx = fmaxf(fmaxf(v0, v1), fmaxf(v2, v3));
          mx = fmaxf(mx, __shfl_xor(mx, 1));
          mx = fmaxf(mx, __shfl_xor(mx, 2));
          mx = fmaxf(mx, __shfl_xor(mx, 4));
          mx = fmaxf(mx, __shfl_xor(mx, 8));
          v0 = __expf(v0 - mx); v1 = __expf(v1 - mx);
          v2 = __expf(v2 - mx); v3 = __expf(v3 - mx);
        }
        er[0][r] = v0; er[1][r] = v1; er[2][r] = v2; er[3][r] = v3;
      }
      int n = rowA0 + wm * 128 + f * 16 + quad * 4;  // 4-aligned, no batch cross
      int b = n >> 13, s = n & 8191;
      int bh = b * NH_ + h;
#pragma unroll
      for (int j = 0; j < 4; ++j) {
        ushort4 o;
        o.x = f2b(er[j][0]); o.y = f2b(er[j][1]);
        o.z = f2b(er[j][2]); o.w = f2b(er[j][3]);
        *(ushort4*)&dstT[((size_t)bh * 64 + j * 16 + l16) * S_ + s] = o;
      }
    }
  }
}

// ---------- K5: kv summary via MFMA: kvT[bh][d][m], row 64 = ksum ----------
// grid (16, 48). A-role = vT rows (d), B-role = kpT rows (m), K = n (512/block).
__global__ __launch_bounds__(256, 4) void kv_accum_mfma(
    const U16* __restrict__ kpT, const U16* __restrict__ vT,
    float* __restrict__ kvT) {
  __shared__ __align__(16) U16 Us[2 * 64 * 64];   // [0:4096]=vT tile, [4096:8192]=kpT tile
  const int tid = threadIdx.x, w = tid >> 6, lane = tid & 63;
  const int quad = lane >> 4, l16 = lane & 15;
  const int bh = blockIdx.y;
  const int n0 = blockIdx.x * 512;
  const U16* srcs[4];
  unsigned ldsoff[4];
#pragma unroll
  for (int t = 0; t < 4; ++t) {
    int c = w * 4 + t, buf = c >> 3;              // 0..15; buf 0 = vT, 1 = kpT
    int r = (c & 7) * 8 + (lane >> 3);
    const U16* base = buf ? kpT : vT;
    srcs[t] = base + ((size_t)bh * 64 + r) * S_ + n0 + (lane & 7) * 8;
    ldsoff[t] = buf * 4096 + (c & 7) * 512;
  }
  f32x4 acc[4] = {};
  float ks[4] = {0.f, 0.f, 0.f, 0.f};
  for (int nc = 0; nc < 512; nc += 64) {
#pragma unroll
    for (int t = 0; t < 4; ++t) gl2lds16(srcs[t] + nc, &Us[ldsoff[t]]);
    __syncthreads();
#pragma unroll
    for (int k0 = 0; k0 < 64; k0 += 32) {
      bf16x8 av = *(const bf16x8*)&Us[(w * 16 + l16) * 64 + k0 + quad * 8];
#pragma unroll
      for (int j = 0; j < 4; ++j) {
        bf16x8 bk = *(const bf16x8*)&Us[4096 + (j * 16 + l16) * 64 + k0 + quad * 8];
        if (w == 0) {
#pragma unroll
          for (int e = 0; e < 8; ++e) ks[j] += b2f((U16)bk[e]);
        }
        acc[j] = __builtin_amdgcn_mfma_f32_16x16x32_bf16(av, bk, acc[j], 0, 0, 0);
      }
    }
    __syncthreads();
  }
#pragma unroll
  for (int j = 0; j < 4; ++j)
#pragma unroll
    for (int r = 0; r < 4; ++r) {
      int d = w * 16 + quad * 4 + r;
      atomicAdd(&kvT[((size_t)bh * 80 + d) * 64 + j * 16 + l16], acc[j][r]);
    }
  if (w == 0) {
#pragma unroll
    for (int j = 0; j < 4; ++j) {
      ks[j] += __shfl_xor(ks[j], 16);
      ks[j] += __shfl_xor(ks[j], 32);
    }
    if (lane < 16) {
#pragma unroll
      for (int j = 0; j < 4; ++j)
        atomicAdd(&kvT[((size_t)bh * 80 + 64) * 64 + j * 16 + lane], ks[j]);
    }
  }
}

// ---------- K6: ctx = (qp @ kv)/(norm+eps); norm = MFMA tile j=4 ----------
__global__ __launch_bounds__(256) void ctx_gemm_k(
    const U16* __restrict__ qp, const float* __restrict__ kvT,
    U16* __restrict__ ctx) {
  __shared__ __align__(16) U16 As[128 * 64];
  __shared__ __align__(16) U16 Bs[80 * 64];
  int bh = blockIdx.y, row0 = blockIdx.x * 128;
  int tid = threadIdx.x, w = tid >> 6, lane = tid & 63;
  int quad = lane >> 4, l16 = lane & 15;
  const U16* Ab = qp + ((size_t)bh * S_ + row0) * 64;
#pragma unroll
  for (int t = 0; t < 4; ++t) {
    int cb = (w * 4 + t) * 64;
    gl2lds16(Ab + (size_t)(cb + lane) * 8, &As[cb * 8]);
  }
  const float4* kv4 = (const float4*)(kvT + (size_t)bh * 5120);
#pragma unroll
  for (int t = 0; t < 5; ++t) {
    int idx = t * 256 + tid;          // 1280 float4s = 80*64 floats
    float4 f = kv4[idx];
    ushort4 o;
    o.x = f2b(f.x); o.y = f2b(f.y); o.z = f2b(f.z); o.w = f2b(f.w);
    *(ushort4*)&Bs[idx * 4] = o;
  }
  __syncthreads();
  f32x4 acc[2][5] = {};
#pragma unroll
  for (int k0 = 0; k0 < 64; k0 += 32) {
    bf16x8 a[2], fb[5];
#pragma unroll
    for (int i = 0; i < 2; ++i)
      a[i] = *(const bf16x8*)&As[(w * 32 + i * 16 + l16) * 64 + k0 + quad * 8];
#pragma unroll
    for (int j = 0; j < 5; ++j)
      fb[j] = *(const bf16x8*)&Bs[(j * 16 + l16) * 64 + k0 + quad * 8];
#pragma unroll
    for (int j = 0; j < 5; ++j)
#pragma unroll
      for (int i = 0; i < 2; ++i)
        acc[i][j] = __builtin_amdgcn_mfma_f32_16x16x32_bf16(a[i], fb[j], acc[i][j], 0, 0, 0);
  }
  int b = bh / NH_, h = bh - b * NH_;
#pragma unroll
  for (int i = 0; i < 2; ++i) {
#pragma unroll
    for (int r = 0; r < 4; ++r) {
      int s = row0 + w * 32 + i * 16 + quad * 4 + r;
      float nv = __shfl(acc[i][4][r], lane & 48);   // col 64 (l16==0) = norm(row)
      float inv = 1.f / (nv + EPS_);
      size_t base = ((size_t)b * S_ + s) * H_ + h * 64;
#pragma unroll
      for (int j = 0; j < 4; ++j)
        ctx[base + j * 16 + l16] = f2b(acc[i][j][r] * inv);
    }
  }
}

// ---------- K7: pipelined 256^2 bf16 GEMM (output projection) ----------
__global__ __launch_bounds__(512, 2) void gemm_out(
    const U16* __restrict__ Ahi, const U16* __restrict__ Bhi,
    const float* __restrict__ bias, float* __restrict__ C) {
  __shared__ __align__(16) U16 Us[65536];
  const int tid = threadIdx.x, w = tid >> 6, lane = tid & 63;
  const int quad = lane >> 4, l16 = lane & 15;
  const int id = blockIdx.x;
  const int swz = (id & 7) * 48 + (id >> 3);         // 384 = 8*48, bijective
  const int mt = swz & 127, nt = swz >> 7;
  const int rowA0 = mt * 256, colB0 = nt * 256;
  const int wm = w >> 2, wn = w & 3;
  const int srow = w * 8 + (lane >> 3);
  const int kch = ((lane & 7) ^ (lane >> 3)) * 8;
  const U16* As = Ahi + (size_t)(rowA0 + srow) * H_ + kch;
  const U16* Bs = Bhi + (size_t)(colB0 + srow) * H_ + kch;
  const unsigned lb = (unsigned)(w * 8) * 64;

  f32x4 acc[8][4] = {};

  auto stage = [&](int kt, int bi) {
    const U16* ap = As + kt * 64;
    const U16* bp = Bs + kt * 64;
    unsigned ub = (unsigned)bi * 32768u + lb;
#pragma unroll
    for (int q = 0; q < 4; ++q) {
      gl2lds16(ap + (size_t)(q * 64) * H_, &Us[ub + q * 4096]);
      gl2lds16(bp + (size_t)(q * 64) * H_, &Us[ub + 16384u + q * 4096]);
    }
  };

  stage(0, 0);
  stage(1, 1);
  for (int t = 0; t < 12; ++t) {
    const unsigned ab = (unsigned)(t & 1) * 32768u;
    if (t < 11) asm volatile("s_waitcnt vmcnt(8)" ::: "memory");
    else        asm volatile("s_waitcnt vmcnt(0)" ::: "memory");
    __builtin_amdgcn_sched_barrier(0);
    __builtin_amdgcn_s_barrier();
    __builtin_amdgcn_sched_barrier(0);
#pragma unroll
    for (int ks = 0; ks < 2; ++ks) {
      const int xo = ks * 4 + quad;
#pragma unroll
      for (int mh = 0; mh < 2; ++mh) {
        bf16x8 ah[4], bh[4];
#pragma unroll
        for (int i = 0; i < 4; ++i) {
          int row = wm * 128 + mh * 64 + i * 16 + l16;
          ah[i] = *(const bf16x8*)&Us[ab + row * 64 + ((xo ^ (l16 & 7)) * 8)];
        }
#pragma unroll
        for (int j = 0; j < 4; ++j) {
          int row = wn * 64 + j * 16 + l16;
          bh[j] = *(const bf16x8*)&Us[ab + 16384u + row * 64 + ((xo ^ (l16 & 7)) * 8)];
        }
        __builtin_amdgcn_s_setprio(1);
#pragma unroll
        for (int j = 0; j < 4; ++j)
#pragma unroll
          for (int i = 0; i < 4; ++i)
            acc[mh * 4 + i][j] = __builtin_amdgcn_mfma_f32_16x16x32_bf16(
                ah[i], bh[j], acc[mh * 4 + i][j], 0, 0, 0);
        __builtin_amdgcn_s_setprio(0);
      }
    }
    __builtin_amdgcn_sched_barrier(0);
    __builtin_amdgcn_s_barrier();
    __builtin_amdgcn_sched_barrier(0);
    if (t + 2 < 12) stage(t + 2, t & 1);
  }

#pragma unroll
  for (int f = 0; f < 8; ++f) {
    int row = rowA0 + wm * 128 + f * 16 + quad * 4;
#pragma unroll
    for (int j = 0; j < 4; ++j) {
      int col = colB0 + wn * 64 + j * 16 + l16;
      float bvv = bias[col];
#pragma unroll
      for (int r = 0; r < 4; ++r)
        C[(size_t)(row + r) * H_ + col] = acc[f][j][r] + bvv;
    }
  }
}

extern "C" void kernel_launch(void* const* d_in, const int* in_sizes, int n_in,
                              void* d_out, int out_size, void* d_ws, size_t ws_size,
                              hipStream_t stream) {
  const float* hs = (const float*)d_in[0];
  const float* Wq = (const float*)d_in[1];
  const float* bq = (const float*)d_in[2];
  const float* Wk = (const float*)d_in[3];
  const float* bk = (const float*)d_in[4];
  const float* Wv = (const float*)d_in[5];
  const float* bv = (const float*)d_in[6];
  const float* Wo = (const float*)d_in[7];
  const float* bo = (const float*)d_in[8];
  const float* P  = (const float*)d_in[9];
  float* out = (float*)d_out;

  char* ws = (char*)d_ws;
  size_t off = 0;
  auto alloc = [&](size_t bytes) -> void* {
    void* p = ws + off;
    off = (off + bytes + 255) & ~(size_t)255;
    return p;
  };
  U16*   hs_hi = (U16*)alloc(50331648);     // [32768,768] bf16 (reused as ctx)
  float* WqpF  = (float*)alloc(2359296);
  float* WkpF  = (float*)alloc(2359296);
  float* bqpF  = (float*)alloc(3072);
  float* bkpF  = (float*)alloc(3072);
  U16*   WcatH = (U16*)alloc(3538944);      // [2304,768] bf16
  U16*   WoTH  = (U16*)alloc(1179648);
  float* biasC = (float*)alloc(9216);
  U16*   qp    = (U16*)alloc(50331648);     // [48,8192,64] bf16 row-major
  U16*   kpT   = (U16*)alloc(50331648);     // [48,64,8192] bf16 transposed
  U16*   vT    = (U16*)alloc(50331648);     // [48,64,8192] bf16 transposed
  float* kvT   = (float*)alloc(983040);     // [48,80,64] fp32 (row 64 = ksum)
  U16*   ctx   = hs_hi;                     // hs dead after QKV GEMM: reuse

  zero_f32<<<dim3(960), dim3(256), 0, stream>>>(kvT, 245760);
  cvt_f32_bf16<<<dim3(24576), dim3(256), 0, stream>>>(hs, hs_hi, 6291456);
  fold_proj<<<dim3(192, 12, 2), dim3(256), 0, stream>>>(Wq, bq, Wk, bk, P, WqpF, bqpF, WkpF, bkpF);
  build_cat<<<dim3(3, 3072), dim3(256), 0, stream>>>(WqpF, WkpF, Wv, Wo, WcatH, WoTH);
  build_bias<<<dim3(9), dim3(256), 0, stream>>>(bqpF, bkpF, bv, biasC);
  gemm_qkv<<<dim3(1152), dim3(512), 0, stream>>>(hs_hi, WcatH, biasC, qp, kpT, vT);
  kv_accum_mfma<<<dim3(16, 48), dim3(256), 0, stream>>>(kpT, vT, kvT);
  ctx_gemm_k<<<dim3(64, 48), dim3(256), 0, stream>>>(qp, kvT, ctx);
  gemm_out<<<dim3(384), dim3(512), 0, stream>>>(ctx, WoTH, bo, out);
}

// Round 2
// 496.199 us; speedup vs baseline: 1.0198x; 1.0198x over previous
//
#include <hip/hip_runtime.h>
#include <hip/hip_bf16.h>

// Performer-style linear attention: B=4, S=8192, H=768, NH=12, HD=64, M=64.
// Round 6: m201-style 4-phase K-loop for gemm_qkv/gemm_out:
//   per K64-tile: stage(t+1 -> other buf); vmcnt(8) counted; barrier;
//   4 phases {ds_reads (B-frags hoisted: 24 reads/tile not 32); barrier;
//   lgkmcnt(0); setprio(1); 16 MFMA; setprio(0); barrier}.
// XCD swizzle fixed: each XCD owns a contiguous 16-mt stripe, nt fastest
// (B panel stays L2-resident; A fetched ~once).
// Pipeline:
//   K0 zero kvT[48][80][64]
//   K1 cvt hs -> bf16
//   K2 fold P into Wq/Wk (Wqp = Wq * blockdiag(P)) [fp32]
//   K3 build B^T concat weights [Wqp|Wkp|Wv] + WoT as bf16, bias
//   K4 bf16 GEMM QKV (256^2, 4-phase) + fused maxexp epilogue
//   K5 kv MFMA: kvT[bh][d][m] = sum_n vT[d][n] kpT[m][n]; row 64 = ksum
//   K6 ctx_gemm: acc = qp @ [kvT|ksum]^T, ctx = acc/(norm+eps) -> bf16
//   K7 bf16 GEMM (256^2, 4-phase): out = ctx @ Wo + bo -> fp32

#define S_    8192
#define H_    768
#define NH_   12
#define EPS_  1e-6f

typedef unsigned short U16;
typedef short bf16x8 __attribute__((ext_vector_type(8)));
typedef float f32x4  __attribute__((ext_vector_type(4)));

__device__ __forceinline__ U16 f2b(float x) {            // fp32 -> bf16 RNE
  unsigned u = __float_as_uint(x);
  return (U16)((u + 0x7fffu + ((u >> 16) & 1u)) >> 16);
}
__device__ __forceinline__ float b2f(U16 h) {
  return __uint_as_float(((unsigned)h) << 16);
}
__device__ __forceinline__ void gl2lds16(const void* g, void* l) {
  __builtin_amdgcn_global_load_lds(
      (const __attribute__((address_space(1))) void*)g,
      (__attribute__((address_space(3))) void*)l, 16, 0, 0);
}

// ---------- K0: zero scratch ----------
__global__ void zero_f32(float* __restrict__ p, int n) {
  int i = blockIdx.x * 256 + threadIdx.x;
  if (i < n) p[i] = 0.f;
}

// ---------- K1: fp32 -> bf16 ----------
__global__ void cvt_f32_bf16(const float* __restrict__ src, U16* __restrict__ hi, int n4) {
  int i = blockIdx.x * 256 + threadIdx.x;
  if (i >= n4) return;
  float4 x = ((const float4*)src)[i];
  ushort4 h;
  h.x = f2b(x.x); h.y = f2b(x.y); h.z = f2b(x.z); h.w = f2b(x.w);
  ((ushort4*)hi)[i] = h;
}

// ---------- K2: fold P into Wq / Wk (and biases) ----------
__global__ void fold_proj(const float* __restrict__ Wq, const float* __restrict__ bq,
                          const float* __restrict__ Wk, const float* __restrict__ bk,
                          const float* __restrict__ P,
                          float* __restrict__ Wqp, float* __restrict__ bqp,
                          float* __restrict__ Wkp, float* __restrict__ bkp) {
  __shared__ float Pl[64 * 64];
  __shared__ float WL[4 * 64];
  int h = blockIdx.y, kc = blockIdx.x, tid = threadIdx.x;
  const float* W  = blockIdx.z ? Wk : Wq;
  const float* bb = blockIdx.z ? bk : bq;
  float* Wout = blockIdx.z ? Wkp : Wqp;
  float* bout = blockIdx.z ? bkp : bqp;
  const float4* P4 = (const float4*)(P + (size_t)h * 4096);
#pragma unroll
  for (int i = 0; i < 4; ++i) ((float4*)Pl)[tid + i * 256] = P4[tid + i * 256];
  WL[tid] = W[(size_t)(kc * 4 + (tid >> 6)) * H_ + h * 64 + (tid & 63)];
  __syncthreads();
  int kl = tid >> 6, m = tid & 63;
  float acc = 0.f;
#pragma unroll
  for (int d = 0; d < 64; ++d) acc += WL[kl * 64 + d] * Pl[d * 64 + m];
  Wout[(size_t)(kc * 4 + kl) * H_ + h * 64 + m] = acc;
  if (kc == 0 && tid < 64) {
    float a2 = 0.f;
    for (int d = 0; d < 64; ++d) a2 += bb[h * 64 + d] * Pl[d * 64 + tid];
    bout[h * 64 + tid] = a2;
  }
}

// ---------- K3: build B^T-layout weights as bf16 ----------
__global__ void build_cat(const float* __restrict__ Wqp, const float* __restrict__ Wkp,
                          const float* __restrict__ Wv,  const float* __restrict__ Wo,
                          U16* __restrict__ WcatH, U16* __restrict__ WoTH) {
  int k = blockIdx.x * 256 + threadIdx.x;
  int r = blockIdx.y;
  float v; U16* dh; size_t off;
  if (r < 768)       { v = Wqp[(size_t)k * H_ + r];          off = (size_t)r * H_ + k;          dh = WcatH; }
  else if (r < 1536) { v = Wkp[(size_t)k * H_ + (r - 768)];  off = (size_t)r * H_ + k;          dh = WcatH; }
  else if (r < 2304) { v = Wv [(size_t)k * H_ + (r - 1536)]; off = (size_t)r * H_ + k;          dh = WcatH; }
  else               { v = Wo [(size_t)k * H_ + (r - 2304)]; off = (size_t)(r - 2304) * H_ + k; dh = WoTH; }
  dh[off] = f2b(v);
}

__global__ void build_bias(const float* __restrict__ bqp, const float* __restrict__ bkp,
                           const float* __restrict__ bv, float* __restrict__ biasC) {
  int i = blockIdx.x * 256 + threadIdx.x;
  if (i >= 2304) return;
  biasC[i] = i < 768 ? bqp[i] : (i < 1536 ? bkp[i - 768] : bv[i - 1536]);
}

// ---- shared GEMM K-loop macro: 256x256 tile, BK=64, 8 waves (2m x 4n),
// per-wave 128x64 output, dbuf LDS, 4-phase m201 schedule.  Expects in scope:
// Us, As, Bs (per-thread global src ptrs), lb, wm, wn, quad, l16, acc[8][4].
#define GEMM_KLOOP()                                                         \
  auto stage = [&](int kt, int bi) {                                         \
    const U16* ap = As + kt * 64;                                            \
    const U16* bp = Bs + kt * 64;                                            \
    unsigned ub = (unsigned)bi * 32768u + lb;                                \
    _Pragma("unroll")                                                        \
    for (int q = 0; q < 4; ++q) {                                            \
      gl2lds16(ap + (size_t)(q * 64) * H_, &Us[ub + q * 4096]);              \
      gl2lds16(bp + (size_t)(q * 64) * H_, &Us[ub + 16384u + q * 4096]);     \
    }                                                                        \
  };                                                                         \
  auto swzo = [&](int ks) { return (((ks * 4 + quad) ^ (l16 & 7)) * 8); };   \
  stage(0, 0);                                                               \
  for (int t = 0; t < 12; ++t) {                                             \
    const unsigned ab = (unsigned)(t & 1) * 32768u;                          \
    if (t < 11) {                                                            \
      stage(t + 1, (t + 1) & 1);                                             \
      asm volatile("s_waitcnt vmcnt(8)" ::: "memory");                       \
    } else {                                                                 \
      asm volatile("s_waitcnt vmcnt(0)" ::: "memory");                       \
    }                                                                        \
    __builtin_amdgcn_sched_barrier(0);                                       \
    __builtin_amdgcn_s_barrier();                                            \
    __builtin_amdgcn_sched_barrier(0);                                       \
    bf16x8 ah[8], bh[4];                                                     \
    /* P1: mh=0, j={0,1} : 8 A reads + 4 B reads */                          \
    _Pragma("unroll")                                                        \
    for (int i = 0; i < 4; ++i)                                              \
      _Pragma("unroll")                                                      \
      for (int ks = 0; ks < 2; ++ks)                                         \
        ah[i * 2 + ks] = *(const bf16x8*)&Us[ab +                            \
            (unsigned)((wm * 128 + i * 16 + l16) * 64 + swzo(ks))];          \
    _Pragma("unroll")                                                        \
    for (int jj = 0; jj < 2; ++jj)                                           \
      _Pragma("unroll")                                                      \
      for (int ks = 0; ks < 2; ++ks)                                         \
        bh[jj * 2 + ks] = *(const bf16x8*)&Us[ab + 16384u +                  \
            (unsigned)((wn * 64 + jj * 16 + l16) * 64 + swzo(ks))];          \
    PHASE_TAIL(0, 0)                                                         \
    /* P2: mh=0, j={2,3} : 4 B reads */                                      \
    _Pragma("unroll")                                                        \
    for (int jj = 0; jj < 2; ++jj)                                           \
      _Pragma("unroll")                                                      \
      for (int ks = 0; ks < 2; ++ks)                                         \
        bh[jj * 2 + ks] = *(const bf16x8*)&Us[ab + 16384u +                  \
            (unsigned)((wn * 64 + (2 + jj) * 16 + l16) * 64 + swzo(ks))];    \
    PHASE_TAIL(0, 1)                                                         \
    /* P3: mh=1, j={2,3} : 8 A reads (bh reused) */                          \
    _Pragma("unroll")                                                        \
    for (int i = 0; i < 4; ++i)                                              \
      _Pragma("unroll")                                                      \
      for (int ks = 0; ks < 2; ++ks)                                         \
        ah[i * 2 + ks] = *(const bf16x8*)&Us[ab +                            \
            (unsigned)((wm * 128 + 64 + i * 16 + l16) * 64 + swzo(ks))];     \
    PHASE_TAIL(1, 1)                                                         \
    /* P4: mh=1, j={0,1} : 4 B reads (ah reused) */                          \
    _Pragma("unroll")                                                        \
    for (int jj = 0; jj < 2; ++jj)                                           \
      _Pragma("unroll")                                                      \
      for (int ks = 0; ks < 2; ++ks)                                         \
        bh[jj * 2 + ks] = *(const bf16x8*)&Us[ab + 16384u +                  \
            (unsigned)((wn * 64 + jj * 16 + l16) * 64 + swzo(ks))];          \
    PHASE_TAIL(1, 0)                                                         \
  }

#define PHASE_TAIL(mh, jh)                                                   \
    __builtin_amdgcn_sched_barrier(0);                                       \
    __builtin_amdgcn_s_barrier();                                            \
    asm volatile("s_waitcnt lgkmcnt(0)" ::: "memory");                       \
    __builtin_amdgcn_sched_barrier(0);                                       \
    __builtin_amdgcn_s_setprio(1);                                           \
    _Pragma("unroll")                                                        \
    for (int jj = 0; jj < 2; ++jj)                                           \
      _Pragma("unroll")                                                      \
      for (int i = 0; i < 4; ++i)                                            \
        _Pragma("unroll")                                                    \
        for (int ks = 0; ks < 2; ++ks)                                       \
          acc[(mh) * 4 + i][(jh) * 2 + jj] =                                 \
              __builtin_amdgcn_mfma_f32_16x16x32_bf16(                       \
                  ah[i * 2 + ks], bh[jj * 2 + ks],                           \
                  acc[(mh) * 4 + i][(jh) * 2 + jj], 0, 0, 0);                \
    __builtin_amdgcn_s_setprio(0);                                           \
    __builtin_amdgcn_sched_barrier(0);                                       \
    __builtin_amdgcn_s_barrier();                                            \
    __builtin_amdgcn_sched_barrier(0);

// ---------- K4: pipelined 256^2 bf16 GEMM + fused maxexp epilogue ----------
__global__ __launch_bounds__(512, 2) void gemm_qkv(
    const U16* __restrict__ Ahi, const U16* __restrict__ Bhi,
    const float* __restrict__ bias,
    U16* __restrict__ qp, U16* __restrict__ kpT, U16* __restrict__ vT) {
  __shared__ __align__(16) U16 Us[65536];            // [buf][mat][256][64]
  const int tid = threadIdx.x, w = tid >> 6, lane = tid & 63;
  const int quad = lane >> 4, l16 = lane & 15;
  const int id = blockIdx.x;
  // XCD-contiguous mt stripes, nt fastest: 1152 = 8 XCD * (16 mt * 9 nt)
  const int xcd = id & 7, pos = id >> 3;
  const int mt = xcd * 16 + pos / 9, nt = pos % 9;
  const int rowA0 = mt * 256, colB0 = nt * 256;
  const int wm = w >> 2, wn = w & 3;
  const int srow = w * 8 + (lane >> 3);              // staging row in 64-group
  const int kch = ((lane & 7) ^ (lane >> 3)) * 8;    // pre-swizzled src chunk
  const U16* As = Ahi + (size_t)(rowA0 + srow) * H_ + kch;
  const U16* Bs = Bhi + (size_t)(colB0 + srow) * H_ + kch;
  const unsigned lb = (unsigned)(w * 8) * 64;

  f32x4 acc[8][4] = {};
  GEMM_KLOOP()

  // epilogue: each wave's 64-col range is exactly one head block
  const int col64 = colB0 + wn * 64;
  float bj[4];
#pragma unroll
  for (int j = 0; j < 4; ++j) bj[j] = bias[col64 + j * 16 + l16];
  if (col64 < 768) {                            // q logits -> row-major qp
    const int h = col64 >> 6;
#pragma unroll
    for (int f = 0; f < 8; ++f) {
#pragma unroll
      for (int r = 0; r < 4; ++r) {
        int row = rowA0 + wm * 128 + f * 16 + quad * 4 + r;
        float v0 = acc[f][0][r] + bj[0], v1 = acc[f][1][r] + bj[1];
        float v2 = acc[f][2][r] + bj[2], v3 = acc[f][3][r] + bj[3];
        float mx = fmaxf(fmaxf(v0, v1), fmaxf(v2, v3));
        mx = fmaxf(mx, __shfl_xor(mx, 1));
        mx = fmaxf(mx, __shfl_xor(mx, 2));
        mx = fmaxf(mx, __shfl_xor(mx, 4));
        mx = fmaxf(mx, __shfl_xor(mx, 8));
        int b = row >> 13, s = row & 8191;
        size_t base = ((size_t)(b * NH_ + h) * S_ + s) * 64 + l16;
        qp[base +  0] = f2b(__expf(v0 - mx));
        qp[base + 16] = f2b(__expf(v1 - mx));
        qp[base + 32] = f2b(__expf(v2 - mx));
        qp[base + 48] = f2b(__expf(v3 - mx));
      }
    }
  } else {                                      // k (exp) or v -> transposed
    const int isv = col64 >= 1536;
    const int h = (col64 - (isv ? 1536 : 768)) >> 6;
    U16* dstT = isv ? vT : kpT;
#pragma unroll
    for (int f = 0; f < 8; ++f) {
      float er[4][4];                           // [j][r]
#pragma unroll
      for (int r = 0; r < 4; ++r) {
        float v0 = acc[f][0][r] + bj[0], v1 = acc[f][1][r] + bj[1];
        float v2 = acc[f][2][r] + bj[2], v3 = acc[f][3][r] + bj[3];
        if (!isv) {
          float mx = fmaxf(fmaxf(v0, v1), fmaxf(v2, v3));
          mx = fmaxf(mx, __shfl_xor(mx, 1));
          mx = fmaxf(mx, __shfl_xor(mx, 2));
          mx = fmaxf(mx, __shfl_xor(mx, 4));
          mx = fmaxf(mx, __shfl_xor(mx, 8));
          v0 = __expf(v0 - mx); v1 = __expf(v1 - mx);
          v2 = __expf(v2 - mx); v3 = __expf(v3 - mx);
        }
        er[0][r] = v0; er[1][r] = v1; er[2][r] = v2; er[3][r] = v3;
      }
      int n = rowA0 + wm * 128 + f * 16 + quad * 4;  // 4-aligned, no batch cross
      int b = n >> 13, s = n & 8191;
      int bh2 = b * NH_ + h;
#pragma unroll
      for (int j = 0; j < 4; ++j) {
        ushort4 o;
        o.x = f2b(er[j][0]); o.y = f2b(er[j][1]);
        o.z = f2b(er[j][2]); o.w = f2b(er[j][3]);
        *(ushort4*)&dstT[((size_t)bh2 * 64 + j * 16 + l16) * S_ + s] = o;
      }
    }
  }
}

// ---------- K5: kv summary via MFMA: kvT[bh][d][m], row 64 = ksum ----------
// grid (16, 48). A-role = vT rows (d), B-role = kpT rows (m), K = n (512/block).
__global__ __launch_bounds__(256, 4) void kv_accum_mfma(
    const U16* __restrict__ kpT, const U16* __restrict__ vT,
    float* __restrict__ kvT) {
  __shared__ __align__(16) U16 Us[2 * 64 * 64];   // [0:4096]=vT tile, [4096:8192]=kpT tile
  const int tid = threadIdx.x, w = tid >> 6, lane = tid & 63;
  const int quad = lane >> 4, l16 = lane & 15;
  const int bh = blockIdx.y;
  const int n0 = blockIdx.x * 512;
  const U16* srcs[4];
  unsigned ldsoff[4];
#pragma unroll
  for (int t = 0; t < 4; ++t) {
    int c = w * 4 + t, buf = c >> 3;              // 0..15; buf 0 = vT, 1 = kpT
    int r = (c & 7) * 8 + (lane >> 3);
    const U16* base = buf ? kpT : vT;
    srcs[t] = base + ((size_t)bh * 64 + r) * S_ + n0 + (lane & 7) * 8;
    ldsoff[t] = buf * 4096 + (c & 7) * 512;
  }
  f32x4 acc[4] = {};
  float ks[4] = {0.f, 0.f, 0.f, 0.f};
  for (int nc = 0; nc < 512; nc += 64) {
#pragma unroll
    for (int t = 0; t < 4; ++t) gl2lds16(srcs[t] + nc, &Us[ldsoff[t]]);
    __syncthreads();
#pragma unroll
    for (int k0 = 0; k0 < 64; k0 += 32) {
      bf16x8 av = *(const bf16x8*)&Us[(w * 16 + l16) * 64 + k0 + quad * 8];
#pragma unroll
      for (int j = 0; j < 4; ++j) {
        bf16x8 bk = *(const bf16x8*)&Us[4096 + (j * 16 + l16) * 64 + k0 + quad * 8];
        if (w == 0) {
#pragma unroll
          for (int e = 0; e < 8; ++e) ks[j] += b2f((U16)bk[e]);
        }
        acc[j] = __builtin_amdgcn_mfma_f32_16x16x32_bf16(av, bk, acc[j], 0, 0, 0);
      }
    }
    __syncthreads();
  }
#pragma unroll
  for (int j = 0; j < 4; ++j)
#pragma unroll
    for (int r = 0; r < 4; ++r) {
      int d = w * 16 + quad * 4 + r;
      atomicAdd(&kvT[((size_t)bh * 80 + d) * 64 + j * 16 + l16], acc[j][r]);
    }
  if (w == 0) {
#pragma unroll
    for (int j = 0; j < 4; ++j) {
      ks[j] += __shfl_xor(ks[j], 16);
      ks[j] += __shfl_xor(ks[j], 32);
    }
    if (lane < 16) {
#pragma unroll
      for (int j = 0; j < 4; ++j)
        atomicAdd(&kvT[((size_t)bh * 80 + 64) * 64 + j * 16 + lane], ks[j]);
    }
  }
}

// ---------- K6: ctx = (qp @ kv)/(norm+eps); norm = MFMA tile j=4 ----------
__global__ __launch_bounds__(256) void ctx_gemm_k(
    const U16* __restrict__ qp, const float* __restrict__ kvT,
    U16* __restrict__ ctx) {
  __shared__ __align__(16) U16 As[128 * 64];
  __shared__ __align__(16) U16 Bs[80 * 64];
  int bh = blockIdx.y, row0 = blockIdx.x * 128;
  int tid = threadIdx.x, w = tid >> 6, lane = tid & 63;
  int quad = lane >> 4, l16 = lane & 15;
  const U16* Ab = qp + ((size_t)bh * S_ + row0) * 64;
#pragma unroll
  for (int t = 0; t < 4; ++t) {
    int cb = (w * 4 + t) * 64;
    gl2lds16(Ab + (size_t)(cb + lane) * 8, &As[cb * 8]);
  }
  const float4* kv4 = (const float4*)(kvT + (size_t)bh * 5120);
#pragma unroll
  for (int t = 0; t < 5; ++t) {
    int idx = t * 256 + tid;          // 1280 float4s = 80*64 floats
    float4 f = kv4[idx];
    ushort4 o;
    o.x = f2b(f.x); o.y = f2b(f.y); o.z = f2b(f.z); o.w = f2b(f.w);
    *(ushort4*)&Bs[idx * 4] = o;
  }
  __syncthreads();
  f32x4 acc[2][5] = {};
#pragma unroll
  for (int k0 = 0; k0 < 64; k0 += 32) {
    bf16x8 a[2], fb[5];
#pragma unroll
    for (int i = 0; i < 2; ++i)
      a[i] = *(const bf16x8*)&As[(w * 32 + i * 16 + l16) * 64 + k0 + quad * 8];
#pragma unroll
    for (int j = 0; j < 5; ++j)
      fb[j] = *(const bf16x8*)&Bs[(j * 16 + l16) * 64 + k0 + quad * 8];
#pragma unroll
    for (int j = 0; j < 5; ++j)
#pragma unroll
      for (int i = 0; i < 2; ++i)
        acc[i][j] = __builtin_amdgcn_mfma_f32_16x16x32_bf16(a[i], fb[j], acc[i][j], 0, 0, 0);
  }
  int b = bh / NH_, h = bh - b * NH_;
#pragma unroll
  for (int i = 0; i < 2; ++i) {
#pragma unroll
    for (int r = 0; r < 4; ++r) {
      int s = row0 + w * 32 + i * 16 + quad * 4 + r;
      float nv = __shfl(acc[i][4][r], lane & 48);   // col 64 (l16==0) = norm(row)
      float inv = 1.f / (nv + EPS_);
      size_t base = ((size_t)b * S_ + s) * H_ + h * 64;
#pragma unroll
      for (int j = 0; j < 4; ++j)
        ctx[base + j * 16 + l16] = f2b(acc[i][j][r] * inv);
    }
  }
}

// ---------- K7: pipelined 256^2 bf16 GEMM (output projection) ----------
__global__ __launch_bounds__(512, 2) void gemm_out(
    const U16* __restrict__ Ahi, const U16* __restrict__ Bhi,
    const float* __restrict__ bias, float* __restrict__ C) {
  __shared__ __align__(16) U16 Us[65536];
  const int tid = threadIdx.x, w = tid >> 6, lane = tid & 63;
  const int quad = lane >> 4, l16 = lane & 15;
  const int id = blockIdx.x;
  // 384 = 8 XCD * (16 mt * 3 nt), mt stripes per XCD, nt fastest
  const int xcd = id & 7, pos = id >> 3;
  const int mt = xcd * 16 + pos / 3, nt = pos % 3;
  const int rowA0 = mt * 256, colB0 = nt * 256;
  const int wm = w >> 2, wn = w & 3;
  const int srow = w * 8 + (lane >> 3);
  const int kch = ((lane & 7) ^ (lane >> 3)) * 8;
  const U16* As = Ahi + (size_t)(rowA0 + srow) * H_ + kch;
  const U16* Bs = Bhi + (size_t)(colB0 + srow) * H_ + kch;
  const unsigned lb = (unsigned)(w * 8) * 64;

  f32x4 acc[8][4] = {};
  GEMM_KLOOP()

#pragma unroll
  for (int f = 0; f < 8; ++f) {
    int row = rowA0 + wm * 128 + f * 16 + quad * 4;
#pragma unroll
    for (int j = 0; j < 4; ++j) {
      int col = colB0 + wn * 64 + j * 16 + l16;
      float bvv = bias[col];
#pragma unroll
      for (int r = 0; r < 4; ++r)
        C[(size_t)(row + r) * H_ + col] = acc[f][j][r] + bvv;
    }
  }
}

extern "C" void kernel_launch(void* const* d_in, const int* in_sizes, int n_in,
                              void* d_out, int out_size, void* d_ws, size_t ws_size,
                              hipStream_t stream) {
  const float* hs = (const float*)d_in[0];
  const float* Wq = (const float*)d_in[1];
  const float* bq = (const float*)d_in[2];
  const float* Wk = (const float*)d_in[3];
  const float* bk = (const float*)d_in[4];
  const float* Wv = (const float*)d_in[5];
  const float* bv = (const float*)d_in[6];
  const float* Wo = (const float*)d_in[7];
  const float* bo = (const float*)d_in[8];
  const float* P  = (const float*)d_in[9];
  float* out = (float*)d_out;

  char* ws = (char*)d_ws;
  size_t off = 0;
  auto alloc = [&](size_t bytes) -> void* {
    void* p = ws + off;
    off = (off + bytes + 255) & ~(size_t)255;
    return p;
  };
  U16*   hs_hi = (U16*)alloc(50331648);     // [32768,768] bf16 (reused as ctx)
  float* WqpF  = (float*)alloc(2359296);
  float* WkpF  = (float*)alloc(2359296);
  float* bqpF  = (float*)alloc(3072);
  float* bkpF  = (float*)alloc(3072);
  U16*   WcatH = (U16*)alloc(3538944);      // [2304,768] bf16
  U16*   WoTH  = (U16*)alloc(1179648);
  float* biasC = (float*)alloc(9216);
  U16*   qp    = (U16*)alloc(50331648);     // [48,8192,64] bf16 row-major
  U16*   kpT   = (U16*)alloc(50331648);     // [48,64,8192] bf16 transposed
  U16*   vT    = (U16*)alloc(50331648);     // [48,64,8192] bf16 transposed
  float* kvT   = (float*)alloc(983040);     // [48,80,64] fp32 (row 64 = ksum)
  U16*   ctx   = hs_hi;                     // hs dead after QKV GEMM: reuse

  zero_f32<<<dim3(960), dim3(256), 0, stream>>>(kvT, 245760);
  cvt_f32_bf16<<<dim3(24576), dim3(256), 0, stream>>>(hs, hs_hi, 6291456);
  fold_proj<<<dim3(192, 12, 2), dim3(256), 0, stream>>>(Wq, bq, Wk, bk, P, WqpF, bqpF, WkpF, bkpF);
  build_cat<<<dim3(3, 3072), dim3(256), 0, stream>>>(WqpF, WkpF, Wv, Wo, WcatH, WoTH);
  build_bias<<<dim3(9), dim3(256), 0, stream>>>(bqpF, bkpF, bv, biasC);
  gemm_qkv<<<dim3(1152), dim3(512), 0, stream>>>(hs_hi, WcatH, biasC, qp, kpT, vT);
  kv_accum_mfma<<<dim3(16, 48), dim3(256), 0, stream>>>(kpT, vT, kvT);
  ctx_gemm_k<<<dim3(64, 48), dim3(256), 0, stream>>>(qp, kvT, ctx);
  gemm_out<<<dim3(384), dim3(512), 0, stream>>>(ctx, WoTH, bo, out);
}